// Round 10
// baseline (131.879 us; speedup 1.0000x reference)
//
#include <hip/hip_runtime.h>

// TimeSeriesAttention B=4,T=4096,D=64 fp32 — all-MFMA pipeline.
//  enc = tanh(softmax(x@W1+b1)@W2+b2)
//  s[j,i]=<x_j,enc_i>; P[j,:] = exp(s)/Z_j ; out[i,d] = sum_j P[j,i] x[j,d]
// Packed layouts (verified rounds 2-9):
//  A/B-frag arrays: [slice(16 rows)][kc(2)][quad(4)][m16][t8] f16
//    (flat: slice*1024 + kc*512 + quad*128 + l15*8)
//  PV-B array xtf (hi-only): [b][slice][quad][d64][4]
// 16x16x32: A[m=l15][k=quad*8+t], B[n=l15][k=quad*8+t], D[col=l15][row=quad*4+r]
// 16x16x16: A/B[idx=l15][k=quad*4+t], same D. C-layout == 16x16x16 A/B-frag
// with k=quad*4+r (the P identity) — reused here to chain MLP layer1->layer2.
//
// Round ledger:
//  R10 intra-wave SW pipeline: REGRESSED (compiler schedule beat it)
//  R11 nsplit 16: NULL — reg-capped at 4 waves/SIMD
//  R12 s_sleep stagger: NULL
//  R13 VALU diet: WIN 58.4->52.6us (shorter load->use stalls)
//  R14/R15 s_setprio: CATASTROPHIC (scratch spill via scheduler fences). Banned.
//  R16 single-product scores+PV in outB: WIN 137.9->122.5us, absmax unchanged.
//  R17 dead-data elimination: small WIN 122.5->121.0us.
//  R18 wpack fused into encode (5->4 dispatches): WIN 121.0->118.3us (-2.7;
//      boundary cost is ~2-3us, not ~10 — revised). Wall decomposition that
//      adds up: 40us harness workspace re-poison fill (in timed region,
//      uncontrollable) + encode ~10 + statsM ~10 + outB ~30 + reduce ~7 +
//      ~20 boundaries. Controllable ~78us.
//  R19 (this): delete the reduce STAGE. outB accumulates straight into out
//      via fp32 atomicAdd (each element gets exactly nsplit=8 adds — low
//      contention, device-scope default). encode zeroes out (4 float4/lane,
//      stream order guarantees visibility). Kills 32MB slab writes + 36MB
//      reduce traffic + 1 boundary; 4->3 dispatches. Numerics: 8-way add
//      order nondeterministic -> last-bit fp32 shifts (~1e-7), far under
//      the 2.44e-4 floor. Predict 118.3 -> ~108-112us.

typedef _Float16 f16;
typedef __attribute__((ext_vector_type(8))) _Float16 f16x8;
typedef __attribute__((ext_vector_type(4))) _Float16 f16x4;
typedef __attribute__((ext_vector_type(4))) float f32x4;

#define TT 4096
#define BB 4
#define BT (BB*TT)
#define SPLIT_A 16
#define NSPLIT 8

#define MFMA32(A,B,C) __builtin_amdgcn_mfma_f32_16x16x32_f16(A,B,C,0,0,0)
#define MFMA16(A,B,C) __builtin_amdgcn_mfma_f32_16x16x16f16(A,B,C,0,0,0)

#if __has_builtin(__builtin_amdgcn_exp2f)
#define EXP2F(x) __builtin_amdgcn_exp2f(x)
#else
#define EXP2F(x) exp2f(x)
#endif

#define LOG2E 1.4426950408889634f

// ---- encode: MFMA MLP, one 16-row slice per wave, no barriers -----------
// W fragments gathered directly from global W1/W2 (wpack fused, R18).
// layer1: D1[m=e1][n=row] = W1frag x xfrag (3-product split)
// softmax over e1 (16 local + shfl_xor 16,32); P1 in C-layout == layer2 B-frag
// layer2: D2[m=e2][n=row] = W2frag x P1frag (3-product split)
// tanh via exp2+rcp. Writes xafh, ench, xtf-hi; zeroes its out rows (R19).
__global__ __launch_bounds__(256, 1) void k_encode(
    const float* __restrict__ x,
    const float* __restrict__ W1, const float* __restrict__ W2,
    const float* __restrict__ b1, const float* __restrict__ b2,
    f16* __restrict__ ench,
    f16* __restrict__ xafh, f16* __restrict__ xtf,
    float* __restrict__ Zbuf, float* __restrict__ out) {
  __shared__ float xS[4][16][68];
  __shared__ float encS[4][16][68];
  int tid = threadIdx.x;
  int w = tid >> 6, lane = tid & 63, quad = lane >> 4, l15 = lane & 15;
  if (tid < 64) Zbuf[blockIdx.x * 64 + tid] = 0.f;
  int slice = blockIdx.x * 4 + w;
  int base = slice * 16;
  // --- zero this wave's out rows (R19: outB atomically accumulates) ---
  {
    const float4 z4 = {0.f, 0.f, 0.f, 0.f};
    float4* po = (float4*)(out + (size_t)(base + l15) * 64 + quad * 16);
    po[0] = z4; po[1] = z4; po[2] = z4; po[3] = z4;
  }
  // --- gather W1 fragments (hi+lo) straight from global (wpack-fused) ---
  f16x8 w1h[4][2], w1l[4][2];
#pragma unroll
  for (int mt = 0; mt < 4; ++mt)
#pragma unroll
    for (int kc = 0; kc < 2; ++kc) {
      f16 h8[8], l8[8];
#pragma unroll
      for (int t = 0; t < 8; ++t) {
        float v = W1[(size_t)(kc * 32 + quad * 8 + t) * 64 + mt * 16 + l15];
        f16 h = (f16)v;
        h8[t] = h; l8[t] = (f16)(v - (float)h);
      }
      w1h[mt][kc] = *(f16x8*)h8;
      w1l[mt][kc] = *(f16x8*)l8;
    }
  // --- gather W2 fragments (hi+lo) ---
  f16x4 w2h[4][4], w2l[4][4];
#pragma unroll
  for (int mt = 0; mt < 4; ++mt)
#pragma unroll
    for (int kt = 0; kt < 4; ++kt) {
      f16 h4[4], l4[4];
#pragma unroll
      for (int t = 0; t < 4; ++t) {
        float v = W2[(size_t)(kt * 16 + quad * 4 + t) * 64 + mt * 16 + l15];
        f16 h = (f16)v;
        h4[t] = h; l4[t] = (f16)(v - (float)h);
      }
      w2h[mt][kt] = *(f16x4*)h4;
      w2l[mt][kt] = *(f16x4*)l4;
    }
  // --- load x as B-frag (== xaf layout), store xafh only, stage xS ---
  f16x8 xbh[2], xbl[2];
#pragma unroll
  for (int kc = 0; kc < 2; ++kc) {
    const float4* p = (const float4*)(x + (size_t)(base + l15) * 64 + kc * 32 + quad * 8);
    float4 v0 = p[0], v1 = p[1];
    float v[8] = {v0.x, v0.y, v0.z, v0.w, v1.x, v1.y, v1.z, v1.w};
    f16 h8[8], l8[8];
#pragma unroll
    for (int t = 0; t < 8; ++t) {
      f16 h = (f16)v[t];
      h8[t] = h; l8[t] = (f16)(v[t] - (float)h);
    }
    xbh[kc] = *(f16x8*)h8;
    xbl[kc] = *(f16x8*)l8;
    size_t off = (size_t)slice * 1024 + kc * 512 + quad * 128 + l15 * 8;
    *(f16x8*)(xafh + off) = xbh[kc];
    *(float4*)&xS[w][l15][kc * 32 + quad * 8] = v0;
    *(float4*)&xS[w][l15][kc * 32 + quad * 8 + 4] = v1;
  }
  // --- layer 1 (3-product) ---
  f32x4 acc1[4];
#pragma unroll
  for (int mt = 0; mt < 4; ++mt) {
    f32x4 z = {0.f, 0.f, 0.f, 0.f};
    acc1[mt] = z;
  }
#pragma unroll
  for (int kc = 0; kc < 2; ++kc)
#pragma unroll
    for (int mt = 0; mt < 4; ++mt) {
      acc1[mt] = MFMA32(w1h[mt][kc], xbh[kc], acc1[mt]);
      acc1[mt] = MFMA32(w1h[mt][kc], xbl[kc], acc1[mt]);
      acc1[mt] = MFMA32(w1l[mt][kc], xbh[kc], acc1[mt]);
    }
  // h1[row=l15][e1=mt*16+quad*4+r] + b1
  float h1[4][4];
#pragma unroll
  for (int mt = 0; mt < 4; ++mt) {
    float4 bv = *(const float4*)(b1 + mt * 16 + quad * 4);
    h1[mt][0] = acc1[mt][0] + bv.x;
    h1[mt][1] = acc1[mt][1] + bv.y;
    h1[mt][2] = acc1[mt][2] + bv.z;
    h1[mt][3] = acc1[mt][3] + bv.w;
  }
  // --- softmax over e1 (per row = l15; values spread over quads) ---
  float m1 = h1[0][0];
#pragma unroll
  for (int mt = 0; mt < 4; ++mt)
#pragma unroll
    for (int r = 0; r < 4; ++r) m1 = fmaxf(m1, h1[mt][r]);
  m1 = fmaxf(m1, __shfl_xor(m1, 16));
  m1 = fmaxf(m1, __shfl_xor(m1, 32));
  float ssum = 0.f;
  float ev[4][4];
#pragma unroll
  for (int mt = 0; mt < 4; ++mt)
#pragma unroll
    for (int r = 0; r < 4; ++r) {
      ev[mt][r] = EXP2F((h1[mt][r] - m1) * LOG2E);
      ssum += ev[mt][r];
    }
  ssum += __shfl_xor(ssum, 16);
  ssum += __shfl_xor(ssum, 32);
  float rs = __builtin_amdgcn_rcpf(ssum);
  // P1 in C-layout == layer-2 B-frag (n=row=l15, k=e1=quad*4+r, ktile=mt)
  f16x4 p1h[4], p1l[4];
#pragma unroll
  for (int mt = 0; mt < 4; ++mt)
#pragma unroll
    for (int r = 0; r < 4; ++r) {
      float p = ev[mt][r] * rs;
      f16 h = (f16)p;
      p1h[mt][r] = h;
      p1l[mt][r] = (f16)(p - (float)h);
    }
  // --- layer 2 (3-product) ---
  f32x4 acc2[4];
#pragma unroll
  for (int mt = 0; mt < 4; ++mt) {
    f32x4 z = {0.f, 0.f, 0.f, 0.f};
    acc2[mt] = z;
  }
#pragma unroll
  for (int kt = 0; kt < 4; ++kt)
#pragma unroll
    for (int mt = 0; mt < 4; ++mt) {
      acc2[mt] = MFMA16(w2h[mt][kt], p1h[kt], acc2[mt]);
      acc2[mt] = MFMA16(w2h[mt][kt], p1l[kt], acc2[mt]);
      acc2[mt] = MFMA16(w2l[mt][kt], p1h[kt], acc2[mt]);
    }
  // enc = tanh(acc2 + b2) * LOG2E; stage to encS[w][row][e2]
#pragma unroll
  for (int mt = 0; mt < 4; ++mt) {
    float4 bv = *(const float4*)(b2 + mt * 16 + quad * 4);
    float bb[4] = {bv.x, bv.y, bv.z, bv.w};
    float o4[4];
#pragma unroll
    for (int r = 0; r < 4; ++r) {
      float hv = acc2[mt][r] + bb[r];
      float ex = EXP2F(hv * (2.0f * LOG2E));
      float th = 1.0f - 2.0f * __builtin_amdgcn_rcpf(ex + 1.0f);
      o4[r] = th * LOG2E;
    }
    *(float4*)&encS[w][l15][mt * 16 + quad * 4] = *(float4*)o4;
  }
  // --- pack ench from encS (hi only; wave-private, lgkmcnt orders it) ---
#pragma unroll
  for (int k = 0; k < 2; ++k) {
    int e = k * 64 + lane;
    int n = e & 15, quad2 = (e >> 4) & 3, kc = e >> 6;
    const float4* p = (const float4*)&encS[w][n][kc * 32 + quad2 * 8];
    float4 v0 = p[0], v1 = p[1];
    float v[8] = {v0.x, v0.y, v0.z, v0.w, v1.x, v1.y, v1.z, v1.w};
    f16 h8[8];
#pragma unroll
    for (int t = 0; t < 8; ++t) h8[t] = (f16)v[t];
    *(f16x8*)(ench + ((size_t)slice * 128 + e) * 8) = *(f16x8*)h8;
  }
  // --- pack xtf (hi only, dense f16x4) from xS: entry [quad'=k][d=lane] ---
  int b = slice >> 8, ls = slice & 255;
#pragma unroll
  for (int k = 0; k < 4; ++k) {
    f16 p4[4];
#pragma unroll
    for (int t = 0; t < 4; ++t) p4[t] = (f16)xS[w][k * 4 + t][lane];
    size_t off = ((((size_t)b * (TT / 16) + ls) * 4 + k) * 64 + lane) * 4;
    *(f16x4*)(xtf + off) = *(f16x4*)p4;
  }
}

// ---- pass A: Z[j] = sum_i exp2(s'[j,i]); single-product f16 scores ------
__global__ __launch_bounds__(512, 4) void k_statsM(
    const f16* __restrict__ xafh, const f16* __restrict__ ench,
    float* __restrict__ Zbuf) {
  int tid = threadIdx.x;
  int w = tid >> 6, lane = tid & 63, quad = lane >> 4, l15 = lane & 15;
  int jb = blockIdx.x * 256 + w * 32;
  int b = jb >> 12;
  f16x8 xa[2][2];
#pragma unroll
  for (int mt = 0; mt < 2; ++mt)
#pragma unroll
    for (int kc = 0; kc < 2; ++kc) {
      size_t off = (size_t)((jb >> 4) + mt) * 1024 + kc * 512 + quad * 128 + l15 * 8;
      xa[mt][kc] = *(const f16x8*)(xafh + off);
    }
  float l_run[8];
#pragma unroll
  for (int s = 0; s < 8; ++s) l_run[s] = 0.f;
  int i0 = blockIdx.y * (TT / SPLIT_A);
  size_t ebase = (size_t)((b * TT + i0) >> 4) * 1024 + quad * 128 + l15 * 8;
  const f16* pEh = ench + ebase;
  for (int it = 0; it < TT / SPLIT_A / 64; ++it) {
    f32x4 acc[2][4];
#pragma unroll
    for (int mt = 0; mt < 2; ++mt)
#pragma unroll
      for (int nt = 0; nt < 4; ++nt) {
        f32x4 z = {0.f, 0.f, 0.f, 0.f};
        acc[mt][nt] = z;
      }
#pragma unroll
    for (int kc = 0; kc < 2; ++kc) {
      f16x8 ebf[4];
#pragma unroll
      for (int nt = 0; nt < 4; ++nt)
        ebf[nt] = *(const f16x8*)(pEh + nt * 1024 + kc * 512);
#pragma unroll
      for (int mt = 0; mt < 2; ++mt)
#pragma unroll
        for (int nt = 0; nt < 4; ++nt)
          acc[mt][nt] = MFMA32(xa[mt][kc], ebf[nt], acc[mt][nt]);
    }
#pragma unroll
    for (int mt = 0; mt < 2; ++mt)
#pragma unroll
      for (int r = 0; r < 4; ++r)
        l_run[mt * 4 + r] += EXP2F(acc[mt][0][r]) + EXP2F(acc[mt][1][r]) +
                             EXP2F(acc[mt][2][r]) + EXP2F(acc[mt][3][r]);
    pEh += 4096;
  }
#pragma unroll
  for (int s = 0; s < 8; ++s) {
    float l = l_run[s];
#pragma unroll
    for (int off = 1; off < 16; off <<= 1) l += __shfl_xor(l, off);
    l_run[s] = l;
  }
  if (l15 == 0) {
#pragma unroll
    for (int mt = 0; mt < 2; ++mt)
#pragma unroll
      for (int r = 0; r < 4; ++r)
        atomicAdd(Zbuf + jb + mt * 16 + quad * 4 + r, l_run[mt * 4 + r]);
  }
}

// ---- pass B: 8 waves share j-stream; wave owns 32 i; 1-product scores +
// 1-product PV. R19: accumulates directly into out via fp32 atomicAdd.
#define OUTB_STEP(CAH, NAH)                                                  \
  {                                                                          \
    f16x4 pvh[4];                                                            \
    _Pragma("unroll") for (int mtb = 0; mtb < 4; ++mtb)                      \
        pvh[mtb] = *(const f16x4*)(pPV + mtb * 64);                          \
    float4 zv = *(const float4*)pZ;                                          \
    float rz[4];                                                             \
    rz[0] = __builtin_amdgcn_rcpf(zv.x);                                     \
    rz[1] = __builtin_amdgcn_rcpf(zv.y);                                     \
    rz[2] = __builtin_amdgcn_rcpf(zv.z);                                     \
    rz[3] = __builtin_amdgcn_rcpf(zv.w);                                     \
    NAH[0] = *(const f16x8*)(pAh);     NAH[1] = *(const f16x8*)(pAh + 512);  \
    f32x4 sacc[2];                                                           \
    _Pragma("unroll") for (int kc = 0; kc < 2; ++kc)                         \
      _Pragma("unroll") for (int nt = 0; nt < 2; ++nt)                       \
          sacc[nt] = MFMA32(CAH[kc], ebr[nt][kc], kc == 0 ? kzero : sacc[nt]); \
    f16x4 pbh[2];                                                            \
    _Pragma("unroll") for (int nt = 0; nt < 2; ++nt)                         \
      _Pragma("unroll") for (int r = 0; r < 4; ++r)                          \
          pbh[nt][r] = (f16)(EXP2F(sacc[nt][r]) * rz[r]);                    \
    _Pragma("unroll") for (int mtb = 0; mtb < 4; ++mtb)                      \
      _Pragma("unroll") for (int nt = 0; nt < 2; ++nt)                       \
          oacc[nt][mtb] = MFMA16(pbh[nt], pvh[mtb], oacc[nt][mtb]);          \
    pAh += 1024; pPV += 1024; pZ += 16;                                      \
  }

__global__ __launch_bounds__(512, 4) void k_outB(
    const f16* __restrict__ xafh, const f16* __restrict__ xtf,
    const f16* __restrict__ ench,
    const float* __restrict__ Zv, float* __restrict__ out, int jlen) {
  int tid = threadIdx.x;
  int w = tid >> 6, lane = tid & 63, quad = lane >> 4, l15 = lane & 15;
  int ibase = blockIdx.x * 256;
  int iw = ibase + w * 32;
  int b = ibase >> 12;
  f16x8 ebr[2][2];
#pragma unroll
  for (int nt = 0; nt < 2; ++nt)
#pragma unroll
    for (int kc = 0; kc < 2; ++kc) {
      size_t off = (size_t)((iw >> 4) + nt) * 1024 + kc * 512 + quad * 128 + l15 * 8;
      ebr[nt][kc] = *(const f16x8*)(ench + off);
    }
  f32x4 oacc[2][4];
#pragma unroll
  for (int nt = 0; nt < 2; ++nt)
#pragma unroll
    for (int mtb = 0; mtb < 4; ++mtb) {
      f32x4 z = {0.f, 0.f, 0.f, 0.f};
      oacc[nt][mtb] = z;
    }
  const f32x4 kzero = {0.f, 0.f, 0.f, 0.f};
  int jt0 = blockIdx.y * jlen;
  int nit = jlen / 16;  // 512/16 = 32 at NSPLIT=8 — always even
  size_t jf0 = (size_t)b * TT + jt0;
  const f16* pAh = xafh + (jf0 >> 4) * 1024 + quad * 128 + l15 * 8;
  const f16* pPV = xtf + ((size_t)b * (TT / 16) + (jt0 >> 4)) * 1024 +
                   quad * 256 + l15 * 4;
  const float* pZ = Zv + jf0 + quad * 4;
  // prologue: tile 0 into the C-slot; pAh advances to tile 1.
  // (last step prefetches one tile past the chunk — lands in the xafl
  //  reservation, still allocated workspace)
  f16x8 cah[2], nah[2];
  cah[0] = *(const f16x8*)(pAh);       cah[1] = *(const f16x8*)(pAh + 512);
  pAh += 1024;
  for (int t = 0; t < nit; t += 2) {
    OUTB_STEP(cah, nah)   // tile t   (prefetch t+1 into n-slot)
    OUTB_STEP(nah, cah)   // tile t+1 (prefetch t+2 into c-slot)
  }
  // R19 epilogue: accumulate into out (each element gets NSPLIT adds total)
#pragma unroll
  for (int nt = 0; nt < 2; ++nt)
#pragma unroll
    for (int r = 0; r < 4; ++r) {
      int i = iw + nt * 16 + quad * 4 + r;
#pragma unroll
      for (int mtb = 0; mtb < 4; ++mtb)
        atomicAdd(out + (size_t)i * 64 + mtb * 16 + l15, oacc[nt][mtb][r]);
    }
}

extern "C" void kernel_launch(void* const* d_in, const int* in_sizes, int n_in,
                              void* d_out, int out_size, void* d_ws,
                              size_t ws_size, hipStream_t stream) {
  const float* x = (const float*)d_in[0];
  const float* W1 = (const float*)d_in[1];
  const float* b1 = (const float*)d_in[2];
  const float* W2 = (const float*)d_in[3];
  const float* b2 = (const float*)d_in[4];
  float* out = (float*)d_out;

  f16* xafh = (f16*)d_ws;                       // 2 MB
  f16* xafl = xafh + (size_t)BT * 64;           // 2 MB (unwritten; prefetch pad)
  f16* xtf  = xafl + (size_t)BT * 64;           // 4 MB reserved (2 MB used)
  f16* ench = xtf + (size_t)BT * 128;           // 2 MB
  f16* encl = ench + (size_t)BT * 64;           // 2 MB (unused)
  float* Zv = (float*)(encl + (size_t)BT * 64); // 64 KB
  (void)ws_size;

  k_encode<<<dim3(BT / 64), dim3(256), 0, stream>>>(
      x, W1, W2, b1, b2, ench, xafh, xtf, Zv, out);
  k_statsM<<<dim3(BT / 256, SPLIT_A), dim3(512), 0, stream>>>(xafh, ench, Zv);
  k_outB<<<dim3(BT / 256, NSPLIT), dim3(512), 0, stream>>>(
      xafh, xtf, ench, Zv, out, TT / NSPLIT);
}

// Round 11
// 116.208 us; speedup vs baseline: 1.1348x; 1.1348x over previous
//
#include <hip/hip_runtime.h>

// TimeSeriesAttention B=4,T=4096,D=64 fp32 — all-MFMA pipeline.
//  enc = tanh(softmax(x@W1+b1)@W2+b2)
//  s[j,i]=<x_j,enc_i>; P[j,:] = exp(s)/Z_j ; out[i,d] = sum_j P[j,i] x[j,d]
// Packed layouts:
//  A/B-frag arrays: [slice(16 rows)][kc(2)][quad(4)][m16][t8] f16
//    (flat: slice*1024 + kc*512 + quad*128 + l15*8)
//  PV-B array xtf (hi-only): [b][slice][quad][d64][4]
// 16x16x32: A[m=l15][k=quad*8+t], B[n=l15][k=quad*8+t], D[col=l15][row=quad*4+r]
// 16x16x16: A/B[idx=l15][k=quad*4+t], same D.
//
// Round ledger:
//  R10 intra-wave SW pipeline: REGRESSED. R11 nsplit16: NULL (reg-capped
//  4 waves/SIMD). R12 stagger: NULL. R13 VALU diet: WIN 58.4->52.6.
//  R14/R15 setprio: CATASTROPHIC (spill). Banned.
//  R16 single-product scores+PV: WIN 137.9->122.5. R17 dead-data: 122.5->121.
//  R18 wpack fused (boundaries are ~2-3us not 10): 121->118.3.
//  R19 atomicAdd-into-out (delete reduce): REGRESSED 118.3->131.9 — 8.4M
//      atomics = same 32MB write volume at RMW throughput on outB's critical
//      path (outB 51us, MfmaUtil 19%). REVERTED to slabs+reduce. Banned.
//      BUT counters localized outB's real limiter: 16 waves/CU x 4.3KB/iter
//      = 66KB/CU-round of loads, 8x redundant (8 waves of a block read the
//      SAME A/pv/Z tiles) ~1030 L1-cy vs 620 MFMA-cy => L1-load-bound.
//      Also explains R11/R12 nulls (didn't change per-CU load volume).
//  R20 (this): LDS-stage the j-stream once per block. Per 4KB j-tile:
//      threads 0-255 load one f16x8 each (T14 split: issue loads -> consume
//      current from LDS -> ds_write next buf -> 1 barrier), double-buffered
//      (8KB LDS). ds_read_b128/b64 at minimum bank aliasing (verified).
//      Per-CU LDS ~576cy/round < 620 MFMA => loads off critical path.
//      Over-reads past chunk end land in allocated pads. Z stays global.
//      Predict outB ~22 -> ~13-16us, MfmaUtil -> 60%+, total -> ~108-112us;
//      absmax bit-identical. If total >=116: revert, floor or statsM next.

typedef _Float16 f16;
typedef __attribute__((ext_vector_type(8))) _Float16 f16x8;
typedef __attribute__((ext_vector_type(4))) _Float16 f16x4;
typedef __attribute__((ext_vector_type(4))) float f32x4;

#define TT 4096
#define BB 4
#define BT (BB*TT)
#define SPLIT_A 16

#define MFMA32(A,B,C) __builtin_amdgcn_mfma_f32_16x16x32_f16(A,B,C,0,0,0)
#define MFMA16(A,B,C) __builtin_amdgcn_mfma_f32_16x16x16f16(A,B,C,0,0,0)

#if __has_builtin(__builtin_amdgcn_exp2f)
#define EXP2F(x) __builtin_amdgcn_exp2f(x)
#else
#define EXP2F(x) exp2f(x)
#endif

#define LOG2E 1.4426950408889634f

// ---- encode: MFMA MLP, one 16-row slice per wave, no barriers -----------
// W fragments gathered directly from global W1/W2 (wpack fused, R18).
__global__ __launch_bounds__(256, 1) void k_encode(
    const float* __restrict__ x,
    const float* __restrict__ W1, const float* __restrict__ W2,
    const float* __restrict__ b1, const float* __restrict__ b2,
    f16* __restrict__ ench,
    f16* __restrict__ xafh, f16* __restrict__ xtf,
    float* __restrict__ Zbuf) {
  __shared__ float xS[4][16][68];
  __shared__ float encS[4][16][68];
  int tid = threadIdx.x;
  int w = tid >> 6, lane = tid & 63, quad = lane >> 4, l15 = lane & 15;
  if (tid < 64) Zbuf[blockIdx.x * 64 + tid] = 0.f;
  int slice = blockIdx.x * 4 + w;
  int base = slice * 16;
  // --- gather W1 fragments (hi+lo) straight from global (wpack-fused) ---
  f16x8 w1h[4][2], w1l[4][2];
#pragma unroll
  for (int mt = 0; mt < 4; ++mt)
#pragma unroll
    for (int kc = 0; kc < 2; ++kc) {
      f16 h8[8], l8[8];
#pragma unroll
      for (int t = 0; t < 8; ++t) {
        float v = W1[(size_t)(kc * 32 + quad * 8 + t) * 64 + mt * 16 + l15];
        f16 h = (f16)v;
        h8[t] = h; l8[t] = (f16)(v - (float)h);
      }
      w1h[mt][kc] = *(f16x8*)h8;
      w1l[mt][kc] = *(f16x8*)l8;
    }
  // --- gather W2 fragments (hi+lo) ---
  f16x4 w2h[4][4], w2l[4][4];
#pragma unroll
  for (int mt = 0; mt < 4; ++mt)
#pragma unroll
    for (int kt = 0; kt < 4; ++kt) {
      f16 h4[4], l4[4];
#pragma unroll
      for (int t = 0; t < 4; ++t) {
        float v = W2[(size_t)(kt * 16 + quad * 4 + t) * 64 + mt * 16 + l15];
        f16 h = (f16)v;
        h4[t] = h; l4[t] = (f16)(v - (float)h);
      }
      w2h[mt][kt] = *(f16x4*)h4;
      w2l[mt][kt] = *(f16x4*)l4;
    }
  // --- load x as B-frag (== xaf layout), store xafh only, stage xS ---
  f16x8 xbh[2], xbl[2];
#pragma unroll
  for (int kc = 0; kc < 2; ++kc) {
    const float4* p = (const float4*)(x + (size_t)(base + l15) * 64 + kc * 32 + quad * 8);
    float4 v0 = p[0], v1 = p[1];
    float v[8] = {v0.x, v0.y, v0.z, v0.w, v1.x, v1.y, v1.z, v1.w};
    f16 h8[8], l8[8];
#pragma unroll
    for (int t = 0; t < 8; ++t) {
      f16 h = (f16)v[t];
      h8[t] = h; l8[t] = (f16)(v[t] - (float)h);
    }
    xbh[kc] = *(f16x8*)h8;
    xbl[kc] = *(f16x8*)l8;
    size_t off = (size_t)slice * 1024 + kc * 512 + quad * 128 + l15 * 8;
    *(f16x8*)(xafh + off) = xbh[kc];
    *(float4*)&xS[w][l15][kc * 32 + quad * 8] = v0;
    *(float4*)&xS[w][l15][kc * 32 + quad * 8 + 4] = v1;
  }
  // --- layer 1 (3-product) ---
  f32x4 acc1[4];
#pragma unroll
  for (int mt = 0; mt < 4; ++mt) {
    f32x4 z = {0.f, 0.f, 0.f, 0.f};
    acc1[mt] = z;
  }
#pragma unroll
  for (int kc = 0; kc < 2; ++kc)
#pragma unroll
    for (int mt = 0; mt < 4; ++mt) {
      acc1[mt] = MFMA32(w1h[mt][kc], xbh[kc], acc1[mt]);
      acc1[mt] = MFMA32(w1h[mt][kc], xbl[kc], acc1[mt]);
      acc1[mt] = MFMA32(w1l[mt][kc], xbh[kc], acc1[mt]);
    }
  // h1[row=l15][e1=mt*16+quad*4+r] + b1
  float h1[4][4];
#pragma unroll
  for (int mt = 0; mt < 4; ++mt) {
    float4 bv = *(const float4*)(b1 + mt * 16 + quad * 4);
    h1[mt][0] = acc1[mt][0] + bv.x;
    h1[mt][1] = acc1[mt][1] + bv.y;
    h1[mt][2] = acc1[mt][2] + bv.z;
    h1[mt][3] = acc1[mt][3] + bv.w;
  }
  // --- softmax over e1 (per row = l15; values spread over quads) ---
  float m1 = h1[0][0];
#pragma unroll
  for (int mt = 0; mt < 4; ++mt)
#pragma unroll
    for (int r = 0; r < 4; ++r) m1 = fmaxf(m1, h1[mt][r]);
  m1 = fmaxf(m1, __shfl_xor(m1, 16));
  m1 = fmaxf(m1, __shfl_xor(m1, 32));
  float ssum = 0.f;
  float ev[4][4];
#pragma unroll
  for (int mt = 0; mt < 4; ++mt)
#pragma unroll
    for (int r = 0; r < 4; ++r) {
      ev[mt][r] = EXP2F((h1[mt][r] - m1) * LOG2E);
      ssum += ev[mt][r];
    }
  ssum += __shfl_xor(ssum, 16);
  ssum += __shfl_xor(ssum, 32);
  float rs = __builtin_amdgcn_rcpf(ssum);
  // P1 in C-layout == layer-2 B-frag (n=row=l15, k=e1=quad*4+r, ktile=mt)
  f16x4 p1h[4], p1l[4];
#pragma unroll
  for (int mt = 0; mt < 4; ++mt)
#pragma unroll
    for (int r = 0; r < 4; ++r) {
      float p = ev[mt][r] * rs;
      f16 h = (f16)p;
      p1h[mt][r] = h;
      p1l[mt][r] = (f16)(p - (float)h);
    }
  // --- layer 2 (3-product) ---
  f32x4 acc2[4];
#pragma unroll
  for (int mt = 0; mt < 4; ++mt) {
    f32x4 z = {0.f, 0.f, 0.f, 0.f};
    acc2[mt] = z;
  }
#pragma unroll
  for (int kt = 0; kt < 4; ++kt)
#pragma unroll
    for (int mt = 0; mt < 4; ++mt) {
      acc2[mt] = MFMA16(w2h[mt][kt], p1h[kt], acc2[mt]);
      acc2[mt] = MFMA16(w2h[mt][kt], p1l[kt], acc2[mt]);
      acc2[mt] = MFMA16(w2l[mt][kt], p1h[kt], acc2[mt]);
    }
  // enc = tanh(acc2 + b2) * LOG2E; stage to encS[w][row][e2]
#pragma unroll
  for (int mt = 0; mt < 4; ++mt) {
    float4 bv = *(const float4*)(b2 + mt * 16 + quad * 4);
    float bb[4] = {bv.x, bv.y, bv.z, bv.w};
    float o4[4];
#pragma unroll
    for (int r = 0; r < 4; ++r) {
      float hv = acc2[mt][r] + bb[r];
      float ex = EXP2F(hv * (2.0f * LOG2E));
      float th = 1.0f - 2.0f * __builtin_amdgcn_rcpf(ex + 1.0f);
      o4[r] = th * LOG2E;
    }
    *(float4*)&encS[w][l15][mt * 16 + quad * 4] = *(float4*)o4;
  }
  // --- pack ench from encS (hi only; wave-private, lgkmcnt orders it) ---
#pragma unroll
  for (int k = 0; k < 2; ++k) {
    int e = k * 64 + lane;
    int n = e & 15, quad2 = (e >> 4) & 3, kc = e >> 6;
    const float4* p = (const float4*)&encS[w][n][kc * 32 + quad2 * 8];
    float4 v0 = p[0], v1 = p[1];
    float v[8] = {v0.x, v0.y, v0.z, v0.w, v1.x, v1.y, v1.z, v1.w};
    f16 h8[8];
#pragma unroll
    for (int t = 0; t < 8; ++t) h8[t] = (f16)v[t];
    *(f16x8*)(ench + ((size_t)slice * 128 + e) * 8) = *(f16x8*)h8;
  }
  // --- pack xtf (hi only, dense f16x4) from xS: entry [quad'=k][d=lane] ---
  int b = slice >> 8, ls = slice & 255;
#pragma unroll
  for (int k = 0; k < 4; ++k) {
    f16 p4[4];
#pragma unroll
    for (int t = 0; t < 4; ++t) p4[t] = (f16)xS[w][k * 4 + t][lane];
    size_t off = ((((size_t)b * (TT / 16) + ls) * 4 + k) * 64 + lane) * 4;
    *(f16x4*)(xtf + off) = *(f16x4*)p4;
  }
}

// ---- pass A: Z[j] = sum_i exp2(s'[j,i]); single-product f16 scores ------
__global__ __launch_bounds__(512, 4) void k_statsM(
    const f16* __restrict__ xafh, const f16* __restrict__ ench,
    float* __restrict__ Zbuf) {
  int tid = threadIdx.x;
  int w = tid >> 6, lane = tid & 63, quad = lane >> 4, l15 = lane & 15;
  int jb = blockIdx.x * 256 + w * 32;
  int b = jb >> 12;
  f16x8 xa[2][2];
#pragma unroll
  for (int mt = 0; mt < 2; ++mt)
#pragma unroll
    for (int kc = 0; kc < 2; ++kc) {
      size_t off = (size_t)((jb >> 4) + mt) * 1024 + kc * 512 + quad * 128 + l15 * 8;
      xa[mt][kc] = *(const f16x8*)(xafh + off);
    }
  float l_run[8];
#pragma unroll
  for (int s = 0; s < 8; ++s) l_run[s] = 0.f;
  int i0 = blockIdx.y * (TT / SPLIT_A);
  size_t ebase = (size_t)((b * TT + i0) >> 4) * 1024 + quad * 128 + l15 * 8;
  const f16* pEh = ench + ebase;
  for (int it = 0; it < TT / SPLIT_A / 64; ++it) {
    f32x4 acc[2][4];
#pragma unroll
    for (int mt = 0; mt < 2; ++mt)
#pragma unroll
      for (int nt = 0; nt < 4; ++nt) {
        f32x4 z = {0.f, 0.f, 0.f, 0.f};
        acc[mt][nt] = z;
      }
#pragma unroll
    for (int kc = 0; kc < 2; ++kc) {
      f16x8 ebf[4];
#pragma unroll
      for (int nt = 0; nt < 4; ++nt)
        ebf[nt] = *(const f16x8*)(pEh + nt * 1024 + kc * 512);
#pragma unroll
      for (int mt = 0; mt < 2; ++mt)
#pragma unroll
        for (int nt = 0; nt < 4; ++nt)
          acc[mt][nt] = MFMA32(xa[mt][kc], ebf[nt], acc[mt][nt]);
    }
#pragma unroll
    for (int mt = 0; mt < 2; ++mt)
#pragma unroll
      for (int r = 0; r < 4; ++r)
        l_run[mt * 4 + r] += EXP2F(acc[mt][0][r]) + EXP2F(acc[mt][1][r]) +
                             EXP2F(acc[mt][2][r]) + EXP2F(acc[mt][3][r]);
    pEh += 4096;
  }
#pragma unroll
  for (int s = 0; s < 8; ++s) {
    float l = l_run[s];
#pragma unroll
    for (int off = 1; off < 16; off <<= 1) l += __shfl_xor(l, off);
    l_run[s] = l;
  }
  if (l15 == 0) {
#pragma unroll
    for (int mt = 0; mt < 2; ++mt)
#pragma unroll
      for (int r = 0; r < 4; ++r)
        atomicAdd(Zbuf + jb + mt * 16 + quad * 4 + r, l_run[mt * 4 + r]);
  }
}

// ---- pass B: 8 waves share j-stream; wave owns 32 i; 1-product scores +
// 1-product PV. R20: j-stream LDS-staged once per block (dbuf, T14 split:
// issue loads -> consume current -> ds_write next -> 1 barrier/iter).
__global__ __launch_bounds__(512, 4) void k_outB(
    const f16* __restrict__ xafh, const f16* __restrict__ xtf,
    const f16* __restrict__ ench,
    const float* __restrict__ Zv, float* __restrict__ slabs, int jlen) {
  __shared__ f16 sA[2][1024];   // A-tile: [kc][quad][l15][8], 2KB per buf
  __shared__ f16 sPV[2][1024];  // pv-tile: [kq][d64][4], 2KB per buf
  int tid = threadIdx.x;
  int w = tid >> 6, lane = tid & 63, quad = lane >> 4, l15 = lane & 15;
  int ibase = blockIdx.x * 256;
  int iw = ibase + w * 32;
  int b = ibase >> 12;
  f16x8 ebr[2][2];
#pragma unroll
  for (int nt = 0; nt < 2; ++nt)
#pragma unroll
    for (int kc = 0; kc < 2; ++kc) {
      size_t off = (size_t)((iw >> 4) + nt) * 1024 + kc * 512 + quad * 128 + l15 * 8;
      ebr[nt][kc] = *(const f16x8*)(ench + off);
    }
  f32x4 oacc[2][4];
#pragma unroll
  for (int nt = 0; nt < 2; ++nt)
#pragma unroll
    for (int mtb = 0; mtb < 4; ++mtb) {
      f32x4 z = {0.f, 0.f, 0.f, 0.f};
      oacc[nt][mtb] = z;
    }
  const f32x4 kzero = {0.f, 0.f, 0.f, 0.f};
  int jt0 = blockIdx.y * jlen;
  int nit = jlen / 16;
  size_t jf0 = (size_t)b * TT + jt0;
  // staging sources (tile t at +t*1024 f16); over-read of tile nit lands in
  // allocated pads (xafh end -> xafl reservation; xtf used-half -> reserve)
  const f16* gA  = xafh + (jf0 >> 4) * 1024;
  const f16* gPV = xtf + ((size_t)b * (TT / 16) + (jt0 >> 4)) * 1024;
  const float* pZ = Zv + jf0 + quad * 4;
  // stage partition: waves 0-1 load A (threads 0-127, 16B each),
  // waves 2-3 load pv (threads 128-255); waves 4-7 idle in staging.
  bool doA = tid < 128, doPV = tid >= 128 && tid < 256;
  int sidx = doA ? tid * 8 : (tid - 128) * 8;   // f16 index in tile
  // prologue: stage tile 0 into buf0
  {
    f16x8 st;
    if (doA)  st = *(const f16x8*)(gA + sidx);
    if (doPV) st = *(const f16x8*)(gPV + sidx);
    if (doA)  *(f16x8*)&sA[0][sidx] = st;
    if (doPV) *(f16x8*)&sPV[0][sidx] = st;
  }
  __syncthreads();
  for (int t = 0; t < nit; ++t) {
    int cur = t & 1;
    // T14 issue-early: next tile's loads (over-reads 1 tile past end: pads)
    f16x8 st;
    if (doA)  st = *(const f16x8*)(gA + (size_t)(t + 1) * 1024 + sidx);
    if (doPV) st = *(const f16x8*)(gPV + (size_t)(t + 1) * 1024 + sidx);
    // consume current from LDS
    f16x8 ca0 = *(const f16x8*)&sA[cur][quad * 128 + l15 * 8];
    f16x8 ca1 = *(const f16x8*)&sA[cur][512 + quad * 128 + l15 * 8];
    float4 zv = *(const float4*)pZ;
    float rz[4];
    rz[0] = __builtin_amdgcn_rcpf(zv.x);
    rz[1] = __builtin_amdgcn_rcpf(zv.y);
    rz[2] = __builtin_amdgcn_rcpf(zv.z);
    rz[3] = __builtin_amdgcn_rcpf(zv.w);
    f32x4 sacc[2];
#pragma unroll
    for (int nt = 0; nt < 2; ++nt) {
      sacc[nt] = MFMA32(ca0, ebr[nt][0], kzero);
      sacc[nt] = MFMA32(ca1, ebr[nt][1], sacc[nt]);
    }
    f16x4 pbh[2];
#pragma unroll
    for (int nt = 0; nt < 2; ++nt)
#pragma unroll
      for (int r = 0; r < 4; ++r)
        pbh[nt][r] = (f16)(EXP2F(sacc[nt][r]) * rz[r]);
#pragma unroll
    for (int mtb = 0; mtb < 4; ++mtb) {
      f16x4 pvh = *(const f16x4*)&sPV[cur][quad * 256 + mtb * 64 + l15 * 4];
#pragma unroll
      for (int nt = 0; nt < 2; ++nt)
        oacc[nt][mtb] = MFMA16(pbh[nt], pvh, oacc[nt][mtb]);
    }
    // T14 write-late: park next tile in the other buffer
    if (doA)  *(f16x8*)&sA[cur ^ 1][sidx] = st;
    if (doPV) *(f16x8*)&sPV[cur ^ 1][sidx] = st;
    pZ += 16;
    __syncthreads();
  }
  float* slab = slabs + (size_t)blockIdx.y * BT * 64;
#pragma unroll
  for (int nt = 0; nt < 2; ++nt)
#pragma unroll
    for (int r = 0; r < 4; ++r) {
      int i = iw + nt * 16 + quad * 4 + r;
#pragma unroll
      for (int mtb = 0; mtb < 4; ++mtb)
        slab[(size_t)i * 64 + mtb * 16 + l15] = oacc[nt][mtb][r];
    }
}

// ---- reduce slabs -> out -------------------------------------------------
__global__ __launch_bounds__(256) void k_reduce(const float* __restrict__ slabs,
                                                float* __restrict__ out,
                                                int nsplit) {
  int e = (blockIdx.x * 256 + threadIdx.x) * 4;
  float4 acc = *(const float4*)(slabs + e);
  for (int s = 1; s < nsplit; ++s) {
    float4 v = *(const float4*)(slabs + (size_t)s * BT * 64 + e);
    acc.x += v.x; acc.y += v.y; acc.z += v.z; acc.w += v.w;
  }
  *(float4*)(out + e) = acc;
}

extern "C" void kernel_launch(void* const* d_in, const int* in_sizes, int n_in,
                              void* d_out, int out_size, void* d_ws,
                              size_t ws_size, hipStream_t stream) {
  const float* x = (const float*)d_in[0];
  const float* W1 = (const float*)d_in[1];
  const float* b1 = (const float*)d_in[2];
  const float* W2 = (const float*)d_in[3];
  const float* b2 = (const float*)d_in[4];
  float* out = (float*)d_out;

  f16* xafh = (f16*)d_ws;                       // 2 MB
  f16* xafl = xafh + (size_t)BT * 64;           // 2 MB (unwritten; prefetch pad)
  f16* xtf  = xafl + (size_t)BT * 64;           // 4 MB reserved (2 MB used)
  f16* ench = xtf + (size_t)BT * 128;           // 2 MB
  f16* encl = ench + (size_t)BT * 64;           // 2 MB (unused)
  float* Zv = (float*)(encl + (size_t)BT * 64); // 64 KB
  f16* w1fh = (f16*)(Zv + BT);                  // 8 KB each (pad)
  f16* w1fl = w1fh + 4096;
  f16* w2fh = w1fl + 4096;
  f16* w2fl = w2fh + 4096;
  float* slabs = (float*)(w2fl + 4096);         // nsplit * 4 MB

  size_t base_bytes = (size_t)((char*)slabs - (char*)d_ws);
  size_t slab_bytes = (size_t)BT * 64 * sizeof(float);
  int nsplit = 8;
  while (nsplit > 1 && base_bytes + (size_t)nsplit * slab_bytes > ws_size)
    nsplit >>= 1;

  k_encode<<<dim3(BT / 64), dim3(256), 0, stream>>>(
      x, W1, W2, b1, b2, ench, xafh, xtf, Zv);
  k_statsM<<<dim3(BT / 256, SPLIT_A), dim3(512), 0, stream>>>(xafh, ench, Zv);
  k_outB<<<dim3(BT / 256, nsplit), dim3(512), 0, stream>>>(
      xafh, xtf, ench, Zv, slabs, TT / nsplit);
  k_reduce<<<dim3(BT * 64 / 1024), dim3(256), 0, stream>>>(slabs, out, nsplit);
}

// Round 12
// 114.878 us; speedup vs baseline: 1.1480x; 1.0116x over previous
//
#include <hip/hip_runtime.h>

// TimeSeriesAttention B=4,T=4096,D=64 fp32 — all-MFMA pipeline.
//  enc = tanh(softmax(x@W1+b1)@W2+b2)
//  s[j,i]=<x_j,enc_i>; P[j,:] = exp(s)/Z_j ; out[i,d] = sum_j P[j,i] x[j,d]
// Packed layouts:
//  A/B-frag arrays: [slice(16 rows)][kc(2)][quad(4)][m16][t8] f16
//    (flat: slice*1024 + kc*512 + quad*128 + l15*8)
//  PV-B array xtf (hi-only): [b][slice][quad][d64][4]
// 16x16x32: A[m=l15][k=quad*8+t], B[n=l15][k=quad*8+t], D[col=l15][row=quad*4+r]
// 16x16x16: A/B[idx=l15][k=quad*4+t], same D.
//
// Round ledger:
//  R10 SW pipeline: REGRESSED. R11 nsplit16: NULL (reg-cap 4 waves/SIMD).
//  R12 stagger: NULL. R13 VALU diet: WIN 58.4->52.6.
//  R14/R15 setprio: CATASTROPHIC (spill). Banned.
//  R16 single-product scores+PV: WIN 137.9->122.5. R17 dead-data: ->121.
//  R18 wpack fused (boundaries ~2-3us): ->118.3.
//  R19 atomicAdd-into-out: REGRESSED (RMW on critical path). Banned.
//      Counters localized outB as L1-bound on 8x-redundant j-stream loads.
//  R20 outB LDS-staging (dbuf, T14): WIN 118.3->116.2 (redundancy cost ~2-3us
//      of wall, partially hidden by wave overlap; absmax bit-identical).
//  R21 (this): same disease in statsM — ebase has NO dependence on w: all
//      8 waves stream the SAME 32KB ench i-chunk (8x redundant, 256KB/block
//      L1 traffic). Fix with the R20 recipe, simpler: stage the full 32KB
//      chunk once up-front (512 thr x 16B x 4 rounds, 1 barrier, no dbuf,
//      no over-read), compute's ebf reads from LDS. xa loads (wave-unique)
//      and atomic epilogue unchanged => bit-identical output.
//      Predict statsM ~10-14 -> ~6-8us, total -> ~110-113; absmax exactly
//      2.441e-4. If <2us: statsM insignificant -> coop fusion or floor.

typedef _Float16 f16;
typedef __attribute__((ext_vector_type(8))) _Float16 f16x8;
typedef __attribute__((ext_vector_type(4))) _Float16 f16x4;
typedef __attribute__((ext_vector_type(4))) float f32x4;

#define TT 4096
#define BB 4
#define BT (BB*TT)
#define SPLIT_A 16

#define MFMA32(A,B,C) __builtin_amdgcn_mfma_f32_16x16x32_f16(A,B,C,0,0,0)
#define MFMA16(A,B,C) __builtin_amdgcn_mfma_f32_16x16x16f16(A,B,C,0,0,0)

#if __has_builtin(__builtin_amdgcn_exp2f)
#define EXP2F(x) __builtin_amdgcn_exp2f(x)
#else
#define EXP2F(x) exp2f(x)
#endif

#define LOG2E 1.4426950408889634f

// ---- encode: MFMA MLP, one 16-row slice per wave, no barriers -----------
// W fragments gathered directly from global W1/W2 (wpack fused, R18).
__global__ __launch_bounds__(256, 1) void k_encode(
    const float* __restrict__ x,
    const float* __restrict__ W1, const float* __restrict__ W2,
    const float* __restrict__ b1, const float* __restrict__ b2,
    f16* __restrict__ ench,
    f16* __restrict__ xafh, f16* __restrict__ xtf,
    float* __restrict__ Zbuf) {
  __shared__ float xS[4][16][68];
  __shared__ float encS[4][16][68];
  int tid = threadIdx.x;
  int w = tid >> 6, lane = tid & 63, quad = lane >> 4, l15 = lane & 15;
  if (tid < 64) Zbuf[blockIdx.x * 64 + tid] = 0.f;
  int slice = blockIdx.x * 4 + w;
  int base = slice * 16;
  // --- gather W1 fragments (hi+lo) straight from global (wpack-fused) ---
  f16x8 w1h[4][2], w1l[4][2];
#pragma unroll
  for (int mt = 0; mt < 4; ++mt)
#pragma unroll
    for (int kc = 0; kc < 2; ++kc) {
      f16 h8[8], l8[8];
#pragma unroll
      for (int t = 0; t < 8; ++t) {
        float v = W1[(size_t)(kc * 32 + quad * 8 + t) * 64 + mt * 16 + l15];
        f16 h = (f16)v;
        h8[t] = h; l8[t] = (f16)(v - (float)h);
      }
      w1h[mt][kc] = *(f16x8*)h8;
      w1l[mt][kc] = *(f16x8*)l8;
    }
  // --- gather W2 fragments (hi+lo) ---
  f16x4 w2h[4][4], w2l[4][4];
#pragma unroll
  for (int mt = 0; mt < 4; ++mt)
#pragma unroll
    for (int kt = 0; kt < 4; ++kt) {
      f16 h4[4], l4[4];
#pragma unroll
      for (int t = 0; t < 4; ++t) {
        float v = W2[(size_t)(kt * 16 + quad * 4 + t) * 64 + mt * 16 + l15];
        f16 h = (f16)v;
        h4[t] = h; l4[t] = (f16)(v - (float)h);
      }
      w2h[mt][kt] = *(f16x4*)h4;
      w2l[mt][kt] = *(f16x4*)l4;
    }
  // --- load x as B-frag (== xaf layout), store xafh only, stage xS ---
  f16x8 xbh[2], xbl[2];
#pragma unroll
  for (int kc = 0; kc < 2; ++kc) {
    const float4* p = (const float4*)(x + (size_t)(base + l15) * 64 + kc * 32 + quad * 8);
    float4 v0 = p[0], v1 = p[1];
    float v[8] = {v0.x, v0.y, v0.z, v0.w, v1.x, v1.y, v1.z, v1.w};
    f16 h8[8], l8[8];
#pragma unroll
    for (int t = 0; t < 8; ++t) {
      f16 h = (f16)v[t];
      h8[t] = h; l8[t] = (f16)(v[t] - (float)h);
    }
    xbh[kc] = *(f16x8*)h8;
    xbl[kc] = *(f16x8*)l8;
    size_t off = (size_t)slice * 1024 + kc * 512 + quad * 128 + l15 * 8;
    *(f16x8*)(xafh + off) = xbh[kc];
    *(float4*)&xS[w][l15][kc * 32 + quad * 8] = v0;
    *(float4*)&xS[w][l15][kc * 32 + quad * 8 + 4] = v1;
  }
  // --- layer 1 (3-product) ---
  f32x4 acc1[4];
#pragma unroll
  for (int mt = 0; mt < 4; ++mt) {
    f32x4 z = {0.f, 0.f, 0.f, 0.f};
    acc1[mt] = z;
  }
#pragma unroll
  for (int kc = 0; kc < 2; ++kc)
#pragma unroll
    for (int mt = 0; mt < 4; ++mt) {
      acc1[mt] = MFMA32(w1h[mt][kc], xbh[kc], acc1[mt]);
      acc1[mt] = MFMA32(w1h[mt][kc], xbl[kc], acc1[mt]);
      acc1[mt] = MFMA32(w1l[mt][kc], xbh[kc], acc1[mt]);
    }
  // h1[row=l15][e1=mt*16+quad*4+r] + b1
  float h1[4][4];
#pragma unroll
  for (int mt = 0; mt < 4; ++mt) {
    float4 bv = *(const float4*)(b1 + mt * 16 + quad * 4);
    h1[mt][0] = acc1[mt][0] + bv.x;
    h1[mt][1] = acc1[mt][1] + bv.y;
    h1[mt][2] = acc1[mt][2] + bv.z;
    h1[mt][3] = acc1[mt][3] + bv.w;
  }
  // --- softmax over e1 (per row = l15; values spread over quads) ---
  float m1 = h1[0][0];
#pragma unroll
  for (int mt = 0; mt < 4; ++mt)
#pragma unroll
    for (int r = 0; r < 4; ++r) m1 = fmaxf(m1, h1[mt][r]);
  m1 = fmaxf(m1, __shfl_xor(m1, 16));
  m1 = fmaxf(m1, __shfl_xor(m1, 32));
  float ssum = 0.f;
  float ev[4][4];
#pragma unroll
  for (int mt = 0; mt < 4; ++mt)
#pragma unroll
    for (int r = 0; r < 4; ++r) {
      ev[mt][r] = EXP2F((h1[mt][r] - m1) * LOG2E);
      ssum += ev[mt][r];
    }
  ssum += __shfl_xor(ssum, 16);
  ssum += __shfl_xor(ssum, 32);
  float rs = __builtin_amdgcn_rcpf(ssum);
  // P1 in C-layout == layer-2 B-frag (n=row=l15, k=e1=quad*4+r, ktile=mt)
  f16x4 p1h[4], p1l[4];
#pragma unroll
  for (int mt = 0; mt < 4; ++mt)
#pragma unroll
    for (int r = 0; r < 4; ++r) {
      float p = ev[mt][r] * rs;
      f16 h = (f16)p;
      p1h[mt][r] = h;
      p1l[mt][r] = (f16)(p - (float)h);
    }
  // --- layer 2 (3-product) ---
  f32x4 acc2[4];
#pragma unroll
  for (int mt = 0; mt < 4; ++mt) {
    f32x4 z = {0.f, 0.f, 0.f, 0.f};
    acc2[mt] = z;
  }
#pragma unroll
  for (int kt = 0; kt < 4; ++kt)
#pragma unroll
    for (int mt = 0; mt < 4; ++mt) {
      acc2[mt] = MFMA16(w2h[mt][kt], p1h[kt], acc2[mt]);
      acc2[mt] = MFMA16(w2h[mt][kt], p1l[kt], acc2[mt]);
      acc2[mt] = MFMA16(w2l[mt][kt], p1h[kt], acc2[mt]);
    }
  // enc = tanh(acc2 + b2) * LOG2E; stage to encS[w][row][e2]
#pragma unroll
  for (int mt = 0; mt < 4; ++mt) {
    float4 bv = *(const float4*)(b2 + mt * 16 + quad * 4);
    float bb[4] = {bv.x, bv.y, bv.z, bv.w};
    float o4[4];
#pragma unroll
    for (int r = 0; r < 4; ++r) {
      float hv = acc2[mt][r] + bb[r];
      float ex = EXP2F(hv * (2.0f * LOG2E));
      float th = 1.0f - 2.0f * __builtin_amdgcn_rcpf(ex + 1.0f);
      o4[r] = th * LOG2E;
    }
    *(float4*)&encS[w][l15][mt * 16 + quad * 4] = *(float4*)o4;
  }
  // --- pack ench from encS (hi only; wave-private, lgkmcnt orders it) ---
#pragma unroll
  for (int k = 0; k < 2; ++k) {
    int e = k * 64 + lane;
    int n = e & 15, quad2 = (e >> 4) & 3, kc = e >> 6;
    const float4* p = (const float4*)&encS[w][n][kc * 32 + quad2 * 8];
    float4 v0 = p[0], v1 = p[1];
    float v[8] = {v0.x, v0.y, v0.z, v0.w, v1.x, v1.y, v1.z, v1.w};
    f16 h8[8];
#pragma unroll
    for (int t = 0; t < 8; ++t) h8[t] = (f16)v[t];
    *(f16x8*)(ench + ((size_t)slice * 128 + e) * 8) = *(f16x8*)h8;
  }
  // --- pack xtf (hi only, dense f16x4) from xS: entry [quad'=k][d=lane] ---
  int b = slice >> 8, ls = slice & 255;
#pragma unroll
  for (int k = 0; k < 4; ++k) {
    f16 p4[4];
#pragma unroll
    for (int t = 0; t < 4; ++t) p4[t] = (f16)xS[w][k * 4 + t][lane];
    size_t off = ((((size_t)b * (TT / 16) + ls) * 4 + k) * 64 + lane) * 4;
    *(f16x4*)(xtf + off) = *(f16x4*)p4;
  }
}

// ---- pass A: Z[j] = sum_i exp2(s'[j,i]); single-product f16 scores ------
// R21: block's full 32KB ench i-chunk staged to LDS once (was read 8x
// redundantly by the 8 waves — ebase has no w-dependence). xa loads and
// atomic epilogue unchanged; math identical => bit-identical output.
__global__ __launch_bounds__(512, 4) void k_statsM(
    const f16* __restrict__ xafh, const f16* __restrict__ ench,
    float* __restrict__ Zbuf) {
  __shared__ f16 sE[16384];  // 32KB = 16 slices x 1024 f16
  int tid = threadIdx.x;
  int w = tid >> 6, lane = tid & 63, quad = lane >> 4, l15 = lane & 15;
  int jb = blockIdx.x * 256 + w * 32;
  int b = jb >> 12;
  // stage: 16384 f16 = 512 threads x 8 f16 x 4 rounds
  int i0 = blockIdx.y * (TT / SPLIT_A);
  const f16* gE = ench + (size_t)((b * TT + i0) >> 4) * 1024;
#pragma unroll
  for (int rr = 0; rr < 4; ++rr) {
    int idx = (rr * 512 + tid) * 8;
    *(f16x8*)&sE[idx] = *(const f16x8*)(gE + idx);
  }
  f16x8 xa[2][2];
#pragma unroll
  for (int mt = 0; mt < 2; ++mt)
#pragma unroll
    for (int kc = 0; kc < 2; ++kc) {
      size_t off = (size_t)((jb >> 4) + mt) * 1024 + kc * 512 + quad * 128 + l15 * 8;
      xa[mt][kc] = *(const f16x8*)(xafh + off);
    }
  float l_run[8];
#pragma unroll
  for (int s = 0; s < 8; ++s) l_run[s] = 0.f;
  __syncthreads();
  const f16* pEh = sE + quad * 128 + l15 * 8;
  for (int it = 0; it < TT / SPLIT_A / 64; ++it) {
    f32x4 acc[2][4];
#pragma unroll
    for (int mt = 0; mt < 2; ++mt)
#pragma unroll
      for (int nt = 0; nt < 4; ++nt) {
        f32x4 z = {0.f, 0.f, 0.f, 0.f};
        acc[mt][nt] = z;
      }
#pragma unroll
    for (int kc = 0; kc < 2; ++kc) {
      f16x8 ebf[4];
#pragma unroll
      for (int nt = 0; nt < 4; ++nt)
        ebf[nt] = *(const f16x8*)(pEh + nt * 1024 + kc * 512);
#pragma unroll
      for (int mt = 0; mt < 2; ++mt)
#pragma unroll
        for (int nt = 0; nt < 4; ++nt)
          acc[mt][nt] = MFMA32(xa[mt][kc], ebf[nt], acc[mt][nt]);
    }
#pragma unroll
    for (int mt = 0; mt < 2; ++mt)
#pragma unroll
      for (int r = 0; r < 4; ++r)
        l_run[mt * 4 + r] += EXP2F(acc[mt][0][r]) + EXP2F(acc[mt][1][r]) +
                             EXP2F(acc[mt][2][r]) + EXP2F(acc[mt][3][r]);
    pEh += 4096;
  }
#pragma unroll
  for (int s = 0; s < 8; ++s) {
    float l = l_run[s];
#pragma unroll
    for (int off = 1; off < 16; off <<= 1) l += __shfl_xor(l, off);
    l_run[s] = l;
  }
  if (l15 == 0) {
#pragma unroll
    for (int mt = 0; mt < 2; ++mt)
#pragma unroll
      for (int r = 0; r < 4; ++r)
        atomicAdd(Zbuf + jb + mt * 16 + quad * 4 + r, l_run[mt * 4 + r]);
  }
}

// ---- pass B: 8 waves share j-stream; wave owns 32 i; 1-product scores +
// 1-product PV. R20: j-stream LDS-staged once per block (dbuf, T14 split).
__global__ __launch_bounds__(512, 4) void k_outB(
    const f16* __restrict__ xafh, const f16* __restrict__ xtf,
    const f16* __restrict__ ench,
    const float* __restrict__ Zv, float* __restrict__ slabs, int jlen) {
  __shared__ f16 sA[2][1024];   // A-tile: [kc][quad][l15][8], 2KB per buf
  __shared__ f16 sPV[2][1024];  // pv-tile: [kq][d64][4], 2KB per buf
  int tid = threadIdx.x;
  int w = tid >> 6, lane = tid & 63, quad = lane >> 4, l15 = lane & 15;
  int ibase = blockIdx.x * 256;
  int iw = ibase + w * 32;
  int b = ibase >> 12;
  f16x8 ebr[2][2];
#pragma unroll
  for (int nt = 0; nt < 2; ++nt)
#pragma unroll
    for (int kc = 0; kc < 2; ++kc) {
      size_t off = (size_t)((iw >> 4) + nt) * 1024 + kc * 512 + quad * 128 + l15 * 8;
      ebr[nt][kc] = *(const f16x8*)(ench + off);
    }
  f32x4 oacc[2][4];
#pragma unroll
  for (int nt = 0; nt < 2; ++nt)
#pragma unroll
    for (int mtb = 0; mtb < 4; ++mtb) {
      f32x4 z = {0.f, 0.f, 0.f, 0.f};
      oacc[nt][mtb] = z;
    }
  const f32x4 kzero = {0.f, 0.f, 0.f, 0.f};
  int jt0 = blockIdx.y * jlen;
  int nit = jlen / 16;
  size_t jf0 = (size_t)b * TT + jt0;
  const f16* gA  = xafh + (jf0 >> 4) * 1024;
  const f16* gPV = xtf + ((size_t)b * (TT / 16) + (jt0 >> 4)) * 1024;
  const float* pZ = Zv + jf0 + quad * 4;
  bool doA = tid < 128, doPV = tid >= 128 && tid < 256;
  int sidx = doA ? tid * 8 : (tid - 128) * 8;
  {
    f16x8 st;
    if (doA)  st = *(const f16x8*)(gA + sidx);
    if (doPV) st = *(const f16x8*)(gPV + sidx);
    if (doA)  *(f16x8*)&sA[0][sidx] = st;
    if (doPV) *(f16x8*)&sPV[0][sidx] = st;
  }
  __syncthreads();
  for (int t = 0; t < nit; ++t) {
    int cur = t & 1;
    f16x8 st;
    if (doA)  st = *(const f16x8*)(gA + (size_t)(t + 1) * 1024 + sidx);
    if (doPV) st = *(const f16x8*)(gPV + (size_t)(t + 1) * 1024 + sidx);
    f16x8 ca0 = *(const f16x8*)&sA[cur][quad * 128 + l15 * 8];
    f16x8 ca1 = *(const f16x8*)&sA[cur][512 + quad * 128 + l15 * 8];
    float4 zv = *(const float4*)pZ;
    float rz[4];
    rz[0] = __builtin_amdgcn_rcpf(zv.x);
    rz[1] = __builtin_amdgcn_rcpf(zv.y);
    rz[2] = __builtin_amdgcn_rcpf(zv.z);
    rz[3] = __builtin_amdgcn_rcpf(zv.w);
    f32x4 sacc[2];
#pragma unroll
    for (int nt = 0; nt < 2; ++nt) {
      sacc[nt] = MFMA32(ca0, ebr[nt][0], kzero);
      sacc[nt] = MFMA32(ca1, ebr[nt][1], sacc[nt]);
    }
    f16x4 pbh[2];
#pragma unroll
    for (int nt = 0; nt < 2; ++nt)
#pragma unroll
      for (int r = 0; r < 4; ++r)
        pbh[nt][r] = (f16)(EXP2F(sacc[nt][r]) * rz[r]);
#pragma unroll
    for (int mtb = 0; mtb < 4; ++mtb) {
      f16x4 pvh = *(const f16x4*)&sPV[cur][quad * 256 + mtb * 64 + l15 * 4];
#pragma unroll
      for (int nt = 0; nt < 2; ++nt)
        oacc[nt][mtb] = MFMA16(pbh[nt], pvh, oacc[nt][mtb]);
    }
    if (doA)  *(f16x8*)&sA[cur ^ 1][sidx] = st;
    if (doPV) *(f16x8*)&sPV[cur ^ 1][sidx] = st;
    pZ += 16;
    __syncthreads();
  }
  float* slab = slabs + (size_t)blockIdx.y * BT * 64;
#pragma unroll
  for (int nt = 0; nt < 2; ++nt)
#pragma unroll
    for (int r = 0; r < 4; ++r) {
      int i = iw + nt * 16 + quad * 4 + r;
#pragma unroll
      for (int mtb = 0; mtb < 4; ++mtb)
        slab[(size_t)i * 64 + mtb * 16 + l15] = oacc[nt][mtb][r];
    }
}

// ---- reduce slabs -> out -------------------------------------------------
__global__ __launch_bounds__(256) void k_reduce(const float* __restrict__ slabs,
                                                float* __restrict__ out,
                                                int nsplit) {
  int e = (blockIdx.x * 256 + threadIdx.x) * 4;
  float4 acc = *(const float4*)(slabs + e);
  for (int s = 1; s < nsplit; ++s) {
    float4 v = *(const float4*)(slabs + (size_t)s * BT * 64 + e);
    acc.x += v.x; acc.y += v.y; acc.z += v.z; acc.w += v.w;
  }
  *(float4*)(out + e) = acc;
}

extern "C" void kernel_launch(void* const* d_in, const int* in_sizes, int n_in,
                              void* d_out, int out_size, void* d_ws,
                              size_t ws_size, hipStream_t stream) {
  const float* x = (const float*)d_in[0];
  const float* W1 = (const float*)d_in[1];
  const float* b1 = (const float*)d_in[2];
  const float* W2 = (const float*)d_in[3];
  const float* b2 = (const float*)d_in[4];
  float* out = (float*)d_out;

  f16* xafh = (f16*)d_ws;                       // 2 MB
  f16* xafl = xafh + (size_t)BT * 64;           // 2 MB (unwritten; prefetch pad)
  f16* xtf  = xafl + (size_t)BT * 64;           // 4 MB reserved (2 MB used)
  f16* ench = xtf + (size_t)BT * 128;           // 2 MB
  f16* encl = ench + (size_t)BT * 64;           // 2 MB (unused)
  float* Zv = (float*)(encl + (size_t)BT * 64); // 64 KB
  f16* w1fh = (f16*)(Zv + BT);                  // 8 KB each (pad)
  f16* w1fl = w1fh + 4096;
  f16* w2fh = w1fl + 4096;
  f16* w2fl = w2fh + 4096;
  float* slabs = (float*)(w2fl + 4096);         // nsplit * 4 MB

  size_t base_bytes = (size_t)((char*)slabs - (char*)d_ws);
  size_t slab_bytes = (size_t)BT * 64 * sizeof(float);
  int nsplit = 8;
  while (nsplit > 1 && base_bytes + (size_t)nsplit * slab_bytes > ws_size)
    nsplit >>= 1;

  k_encode<<<dim3(BT / 64), dim3(256), 0, stream>>>(
      x, W1, W2, b1, b2, ench, xafh, xtf, Zv);
  k_statsM<<<dim3(BT / 256, SPLIT_A), dim3(512), 0, stream>>>(xafh, ench, Zv);
  k_outB<<<dim3(BT / 256, nsplit), dim3(512), 0, stream>>>(
      xafh, xtf, ench, Zv, slabs, TT / nsplit);
  k_reduce<<<dim3(BT * 64 / 1024), dim3(256), 0, stream>>>(slabs, out, nsplit);
}